// Round 3
// baseline (230.102 us; speedup 1.0000x reference)
//
#include <hip/hip_runtime.h>
#include <hip/hip_bf16.h>

// Fused MHA: B=2, T=2048, C=1024, H=16, dh=64.
// Pipeline: qkv GEMM (fp32 inputs -> bf16 MFMA) -> flash attention -> out GEMM (+bias, fp32 out).
// Workspace use: Q/K/V/Ob bf16 = 32 MiB exactly. If ws_size < that, write sentinel and bail
// (diagnostic: absmax ~= 12345 next round => workspace was the crash cause).

typedef __attribute__((ext_vector_type(4))) float f32x4;
typedef __attribute__((ext_vector_type(8))) __bf16 bf16x8;
typedef __attribute__((ext_vector_type(8))) unsigned short us8;
typedef __attribute__((ext_vector_type(4))) unsigned short us4;

#define LOG2E 1.4426950408889634f

__device__ __forceinline__ unsigned short f2bf(float f) {
    unsigned u = __builtin_bit_cast(unsigned, f);
    u += 0x7fffu + ((u >> 16) & 1u);   // round-to-nearest-even
    return (unsigned short)(u >> 16);
}

__device__ __forceinline__ f32x4 mfma16(us8 a, us8 b, f32x4 c) {
    return __builtin_amdgcn_mfma_f32_16x16x32_bf16(
        __builtin_bit_cast(bf16x8, a), __builtin_bit_cast(bf16x8, b), c, 0, 0, 0);
}

__global__ __launch_bounds__(256) void fill_sentinel(float* __restrict__ out, int n) {
    int i = blockIdx.x * 256 + threadIdx.x;
    if (i < n) out[i] = 12345.0f;
}

// ---------------- shared GEMM core: C[m][n] = sum_k A[m][k]*Bw[n][k] ----------------
// 128x128 tile, BK=64, 256 threads = 4 waves (2x2), wave does 64x64 (4x4 frags of 16x16).
// A/B operands can be fp32 (converted to bf16 while staging) or bf16.
// LDS rows padded to 72 shorts (144 B -> 2-way bank alias on ds_read_b128 = free).
template <bool AF32, bool BF32>
__device__ __forceinline__ void gemm_core(
    const void* __restrict__ Av, const void* __restrict__ Bv,
    int K, int m0, int n0, unsigned short* As, unsigned short* Bs, f32x4 acc[4][4]) {
    const float* Af = (const float*)Av;
    const unsigned short* Ab = (const unsigned short*)Av;
    const float* Bf = (const float*)Bv;
    const unsigned short* Bb = (const unsigned short*)Bv;
    const int tid = threadIdx.x;
    const int lane = tid & 63, wid = tid >> 6;
    const int g = lane >> 4, s = lane & 15;
    const int wr = wid >> 1, wc = wid & 1;
#pragma unroll
    for (int mi = 0; mi < 4; mi++)
#pragma unroll
        for (int ni = 0; ni < 4; ni++) acc[mi][ni] = (f32x4){0.f, 0.f, 0.f, 0.f};
    const int row = tid >> 3, col = (tid & 7) * 8;   // element units (float or short)
    for (int k0 = 0; k0 < K; k0 += 64) {
        us8 av[4], bv[4];
#pragma unroll
        for (int p = 0; p < 4; p++) {
            size_t aoff = (size_t)(m0 + row + p * 32) * K + k0 + col;
            if (AF32) {
                f32x4 v0 = *(const f32x4*)(Af + aoff);
                f32x4 v1 = *(const f32x4*)(Af + aoff + 4);
                av[p] = (us8){ f2bf(v0[0]), f2bf(v0[1]), f2bf(v0[2]), f2bf(v0[3]),
                               f2bf(v1[0]), f2bf(v1[1]), f2bf(v1[2]), f2bf(v1[3]) };
            } else {
                av[p] = *(const us8*)(Ab + aoff);
            }
            size_t boff = (size_t)(n0 + row + p * 32) * K + k0 + col;
            if (BF32) {
                f32x4 v0 = *(const f32x4*)(Bf + boff);
                f32x4 v1 = *(const f32x4*)(Bf + boff + 4);
                bv[p] = (us8){ f2bf(v0[0]), f2bf(v0[1]), f2bf(v0[2]), f2bf(v0[3]),
                               f2bf(v1[0]), f2bf(v1[1]), f2bf(v1[2]), f2bf(v1[3]) };
            } else {
                bv[p] = *(const us8*)(Bb + boff);
            }
        }
        __syncthreads();   // previous iteration's LDS reads done
#pragma unroll
        for (int p = 0; p < 4; p++) {
            *(us8*)(As + (row + p * 32) * 72 + col) = av[p];
            *(us8*)(Bs + (row + p * 32) * 72 + col) = bv[p];
        }
        __syncthreads();
#pragma unroll
        for (int kk = 0; kk < 2; kk++) {
            us8 af[4], bf[4];
#pragma unroll
            for (int mi = 0; mi < 4; mi++)
                af[mi] = *(const us8*)(As + (wr * 64 + mi * 16 + s) * 72 + kk * 32 + g * 8);
#pragma unroll
            for (int ni = 0; ni < 4; ni++)
                bf[ni] = *(const us8*)(Bs + (wc * 64 + ni * 16 + s) * 72 + kk * 32 + g * 8);
#pragma unroll
            for (int mi = 0; mi < 4; mi++)
#pragma unroll
                for (int ni = 0; ni < 4; ni++)
                    acc[mi][ni] = mfma16(af[mi], bf[ni], acc[mi][ni]);
        }
    }
}

// ---------------- QKV projection: X[4096][1024](f32) x W*[1024][1024]^T(f32) ----------------
// grid 768 = 32 bm x 24 bn; bn selects Wq (0-7) / Wk (8-15) / Wv (16-23).
// Epilogue scatters into Q/K/V [B=2][H=16][T=2048][64] bf16; Q pre-scaled by 1/8.
__global__ __launch_bounds__(256) void gemm_qkv(
    const float* __restrict__ X, const float* __restrict__ Wq,
    const float* __restrict__ Wk, const float* __restrict__ Wv,
    unsigned short* __restrict__ Qb, unsigned short* __restrict__ Kb,
    unsigned short* __restrict__ Vb) {
    __shared__ unsigned short As[128 * 72];
    __shared__ unsigned short Bs[128 * 72];
    const int bm = blockIdx.x & 31, bn = blockIdx.x >> 5;   // 32 x 24
    const int m0 = bm * 128;
    const int which = bn >> 3;                 // 0:Q 1:K 2:V
    const int n0 = (bn & 7) * 128;             // row within the selected W
    const float* W = which == 0 ? Wq : (which == 1 ? Wk : Wv);
    unsigned short* dst = which == 0 ? Qb : (which == 1 ? Kb : Vb);
    const float scale = which == 0 ? 0.125f : 1.0f;
    f32x4 acc[4][4];
    gemm_core<true, true>(X, W, 1024, m0, n0, As, Bs, acc);
    const int lane = threadIdx.x & 63, wid = threadIdx.x >> 6;
    const int g = lane >> 4, s = lane & 15, wr = wid >> 1, wc = wid & 1;
#pragma unroll
    for (int mi = 0; mi < 4; mi++)
#pragma unroll
        for (int ni = 0; ni < 4; ni++) {
            int n1 = n0 + wc * 64 + ni * 16 + s;   // 0..1023 within this W
            int hh = n1 >> 6, dd = n1 & 63;
#pragma unroll
            for (int r = 0; r < 4; r++) {
                int mg = m0 + wr * 64 + mi * 16 + 4 * g + r;  // D row = (lane>>4)*4+reg
                int bb = mg >> 11, tt = mg & 2047;
                dst[((size_t)(bb * 16 + hh) * 2048 + tt) * 64 + dd] = f2bf(acc[mi][ni][r] * scale);
            }
        }
}

// ---------------- flash attention (causal) ----------------
// grid 1024: bh = bid>>5 (32), qtile = bid&31. 4 waves; wave w owns q-cols w*16..+15.
// Swapped QK^T: S^T = mfma(K, Q) -> lane holds 16 S values for q = s. P's D-layout
// is redistributed to PV a-frag layout with shuffles; V staged transposed in LDS.
__global__ __launch_bounds__(256) void attn(
    const unsigned short* __restrict__ Qb, const unsigned short* __restrict__ Kb,
    const unsigned short* __restrict__ Vb, unsigned short* __restrict__ Ob) {
    __shared__ unsigned short Ks[64 * 72];  // [k][d], pad 72
    __shared__ unsigned short Vt[64 * 68];  // [d][k], pad 68 (b64 reads)
    const int bh = blockIdx.x >> 5, qt = blockIdx.x & 31;
    const int b = bh >> 4, h = bh & 15;
    const unsigned short* Qp = Qb + (size_t)bh * 2048 * 64;
    const unsigned short* Kp = Kb + (size_t)bh * 2048 * 64;
    const unsigned short* Vp = Vb + (size_t)bh * 2048 * 64;
    const int tid = threadIdx.x, lane = tid & 63, wid = tid >> 6;
    const int g = lane >> 4, s = lane & 15;
    const int q0 = qt * 64;
    const int qg = q0 + wid * 16 + s;        // this lane's q row (for S/P/stats)
    us8 qf[2];                                // Q b-frags (d 0..31, 32..63), pre-scaled
    qf[0] = *(const us8*)(Qp + (size_t)qg * 64 + g * 8);
    qf[1] = *(const us8*)(Qp + (size_t)qg * 64 + 32 + g * 8);
    float m_run = -3.0e38f, l_run = 0.f;
    f32x4 o_acc[4];
#pragma unroll
    for (int db = 0; db < 4; db++) o_acc[db] = (f32x4){0.f, 0.f, 0.f, 0.f};
    const int srow = tid >> 3, scol = (tid & 7) * 8;
    for (int t = 0; t <= qt; ++t) {
        int kv0 = t * 64;
        __syncthreads();   // previous iteration's LDS reads done
#pragma unroll
        for (int p = 0; p < 2; p++) {
            int rr = srow + p * 32;
            us8 kvk = *(const us8*)(Kp + (size_t)(kv0 + rr) * 64 + scol);
            *(us8*)(Ks + rr * 72 + scol) = kvk;
            us8 vv = *(const us8*)(Vp + (size_t)(kv0 + rr) * 64 + scol);
#pragma unroll
            for (int j = 0; j < 8; j++) Vt[(scol + j) * 68 + rr] = vv[j];
        }
        __syncthreads();
        // S^T frags: rows k (4 blocks of 16), cols q (wave's 16)
        float sf[4][4];
#pragma unroll
        for (int f = 0; f < 4; f++) {
            f32x4 a = (f32x4){0.f, 0.f, 0.f, 0.f};
            us8 k0v = *(const us8*)(Ks + (f * 16 + s) * 72 + g * 8);
            us8 k1v = *(const us8*)(Ks + (f * 16 + s) * 72 + 32 + g * 8);
            a = mfma16(k0v, qf[0], a);
            a = mfma16(k1v, qf[1], a);
#pragma unroll
            for (int r = 0; r < 4; r++) sf[f][r] = a[r];
        }
        if (t == qt) {   // causal mask on diagonal tile: k = kv0+f*16+4g+r, q = qg
#pragma unroll
            for (int f = 0; f < 4; f++)
#pragma unroll
                for (int r = 0; r < 4; r++)
                    if (kv0 + f * 16 + 4 * g + r > qg) sf[f][r] = -3.0e38f;
        }
        // online softmax stats per q = s (column): in-lane over 16 + xor16 + xor32
        float mt = -3.0e38f;
#pragma unroll
        for (int f = 0; f < 4; f++)
#pragma unroll
            for (int r = 0; r < 4; r++) mt = fmaxf(mt, sf[f][r]);
        mt = fmaxf(mt, __shfl_xor(mt, 16));
        mt = fmaxf(mt, __shfl_xor(mt, 32));
        float mnew = fmaxf(m_run, mt);
        float alpha = __builtin_amdgcn_exp2f((m_run - mnew) * LOG2E);
        float psum = 0.f;
#pragma unroll
        for (int f = 0; f < 4; f++)
#pragma unroll
            for (int r = 0; r < 4; r++) {
                float p = __builtin_amdgcn_exp2f((sf[f][r] - mnew) * LOG2E);
                sf[f][r] = p;
                psum += p;
            }
        psum += __shfl_xor(psum, 16);
        psum += __shfl_xor(psum, 32);
        l_run = l_run * alpha + psum;
        m_run = mnew;
        // rescale O (O rows are q' = 4g+r -> fetch that column's alpha)
        float al[4];
#pragma unroll
        for (int r = 0; r < 4; r++) al[r] = __shfl(alpha, 4 * g + r, 64);
#pragma unroll
        for (int db = 0; db < 4; db++)
#pragma unroll
            for (int r = 0; r < 4; r++) o_acc[db][r] *= al[r];
        // redistribute P (D-layout) -> PV a-frag layout: lane needs P[q=s][k=kk*32+8g+j]
        us8 pa[2];
#pragma unroll
        for (int kk = 0; kk < 2; kk++) {
#pragma unroll
            for (int j = 0; j < 8; j++) {
                int kl = ((g << 3) + j) & 15;
                int src = ((kl >> 2) << 4) + s;
                float lo = __shfl(sf[kk * 2 + 0][j & 3], src, 64);
                float hi = __shfl(sf[kk * 2 + 1][j & 3], src, 64);
                pa[kk][j] = f2bf((g & 2) ? hi : lo);
            }
        }
        // PV: O[q][d] += P * V ; b-frags from transposed V
#pragma unroll
        for (int db = 0; db < 4; db++) {
            const unsigned short* vrow = Vt + (db * 16 + s) * 68;
            us4 u0 = *(const us4*)(vrow + g * 8);
            us4 u1 = *(const us4*)(vrow + g * 8 + 4);
            us8 vf0 = {u0[0], u0[1], u0[2], u0[3], u1[0], u1[1], u1[2], u1[3]};
            o_acc[db] = mfma16(pa[0], vf0, o_acc[db]);
            us4 u2 = *(const us4*)(vrow + 32 + g * 8);
            us4 u3 = *(const us4*)(vrow + 32 + g * 8 + 4);
            us8 vf1 = {u2[0], u2[1], u2[2], u2[3], u3[0], u3[1], u3[2], u3[3]};
            o_acc[db] = mfma16(pa[1], vf1, o_acc[db]);
        }
    }
    // final: divide by row sum, write O as [B][T][C] bf16
    float li[4];
#pragma unroll
    for (int r = 0; r < 4; r++) li[r] = __shfl(l_run, 4 * g + r, 64);
#pragma unroll
    for (int db = 0; db < 4; db++)
#pragma unroll
        for (int r = 0; r < 4; r++) {
            int qq = q0 + wid * 16 + 4 * g + r;
            float v = o_acc[db][r] / li[r];
            Ob[((size_t)(b * 2048) + qq) * 1024 + h * 64 + db * 16 + s] = f2bf(v);
        }
}

// ---------------- output projection: O[4096][1024](bf16) x Wc[1024][1024]^T(f32) + bc ----------------
__global__ __launch_bounds__(256) void gemm_out(
    const unsigned short* __restrict__ O, const float* __restrict__ Wc,
    const float* __restrict__ bc, float* __restrict__ out) {
    __shared__ unsigned short As[128 * 72];
    __shared__ unsigned short Bs[128 * 72];
    const int bm = blockIdx.x & 31, bn = blockIdx.x >> 5;   // 32 x 8
    const int m0 = bm * 128, n0 = bn * 128;
    f32x4 acc[4][4];
    gemm_core<false, true>(O, Wc, 1024, m0, n0, As, Bs, acc);
    const int lane = threadIdx.x & 63, wid = threadIdx.x >> 6;
    const int g = lane >> 4, s = lane & 15, wr = wid >> 1, wc = wid & 1;
#pragma unroll
    for (int mi = 0; mi < 4; mi++)
#pragma unroll
        for (int ni = 0; ni < 4; ni++) {
            int ng = n0 + wc * 64 + ni * 16 + s;
            float bias = bc[ng];
#pragma unroll
            for (int r = 0; r < 4; r++) {
                int mg = m0 + wr * 64 + mi * 16 + 4 * g + r;
                out[(size_t)mg * 1024 + ng] = acc[mi][ni][r] + bias;
            }
        }
}

extern "C" void kernel_launch(void* const* d_in, const int* in_sizes, int n_in,
                              void* d_out, int out_size, void* d_ws, size_t ws_size,
                              hipStream_t stream) {
    const float* x  = (const float*)d_in[0];
    const float* Wq = (const float*)d_in[1];
    const float* Wk = (const float*)d_in[2];
    const float* Wv = (const float*)d_in[3];
    const float* Wc = (const float*)d_in[4];
    const float* bc = (const float*)d_in[5];
    float* out = (float*)d_out;

    // Workspace: Q,K,V [2,16,2048,64] bf16 + Ob [2,2048,1024] bf16 = 32 MiB.
    if (ws_size < 33554432) {   // diagnostic: sentinel output instead of OOB crash
        fill_sentinel<<<(out_size + 255) / 256, 256, 0, stream>>>(out, out_size);
        return;
    }
    char* w = (char*)d_ws;
    unsigned short* Qb = (unsigned short*)(w);
    unsigned short* Kb = (unsigned short*)(w + 8388608);
    unsigned short* Vb = (unsigned short*)(w + 16777216);
    unsigned short* Ob = (unsigned short*)(w + 25165824);

    gemm_qkv<<<768, 256, 0, stream>>>(x, Wq, Wk, Wv, Qb, Kb, Vb);
    attn<<<1024, 256, 0, stream>>>(Qb, Kb, Vb, Ob);
    gemm_out<<<256, 256, 0, stream>>>(Ob, Wc, bc, out);
}

// Round 4
// 193.137 us; speedup vs baseline: 1.1914x; 1.1914x over previous
//
#include <hip/hip_runtime.h>
#include <hip/hip_bf16.h>

// Fused MHA: B=2, T=2048, C=1024, H=16, dh=64.
// qkv GEMM (fp32->bf16 MFMA) -> V pre-transpose -> flash attention (512thr, QBLK=128,
// reg-prefetch staging) -> out GEMM (+bias, fp32 out).
// Workspace: Q/K/V/Ob bf16 = 32 MiB. V^T scratch lives in d_out (dead until gemm_out).

typedef __attribute__((ext_vector_type(4))) float f32x4;
typedef __attribute__((ext_vector_type(8))) __bf16 bf16x8;
typedef __attribute__((ext_vector_type(8))) unsigned short us8;
typedef __attribute__((ext_vector_type(4))) unsigned short us4;

#define LOG2E 1.4426950408889634f

__device__ __forceinline__ unsigned short f2bf(float f) {
    unsigned u = __builtin_bit_cast(unsigned, f);
    u += 0x7fffu + ((u >> 16) & 1u);   // round-to-nearest-even
    return (unsigned short)(u >> 16);
}

__device__ __forceinline__ f32x4 mfma16(us8 a, us8 b, f32x4 c) {
    return __builtin_amdgcn_mfma_f32_16x16x32_bf16(
        __builtin_bit_cast(bf16x8, a), __builtin_bit_cast(bf16x8, b), c, 0, 0, 0);
}

__global__ __launch_bounds__(256) void fill_sentinel(float* __restrict__ out, int n) {
    int i = blockIdx.x * 256 + threadIdx.x;
    if (i < n) out[i] = 12345.0f;
}

// ---------------- shared GEMM core: C[m][n] = sum_k A[m][k]*Bw[n][k] ----------------
// 128x128 tile, BK=64, 256 threads = 4 waves (2x2), wave does 64x64 (4x4 frags of 16x16).
template <bool AF32, bool BF32>
__device__ __forceinline__ void gemm_core(
    const void* __restrict__ Av, const void* __restrict__ Bv,
    int K, int m0, int n0, unsigned short* As, unsigned short* Bs, f32x4 acc[4][4]) {
    const float* Af = (const float*)Av;
    const unsigned short* Ab = (const unsigned short*)Av;
    const float* Bf = (const float*)Bv;
    const unsigned short* Bb = (const unsigned short*)Bv;
    const int tid = threadIdx.x;
    const int lane = tid & 63, wid = tid >> 6;
    const int g = lane >> 4, s = lane & 15;
    const int wr = wid >> 1, wc = wid & 1;
#pragma unroll
    for (int mi = 0; mi < 4; mi++)
#pragma unroll
        for (int ni = 0; ni < 4; ni++) acc[mi][ni] = (f32x4){0.f, 0.f, 0.f, 0.f};
    const int row = tid >> 3, col = (tid & 7) * 8;
    for (int k0 = 0; k0 < K; k0 += 64) {
        us8 av[4], bv[4];
#pragma unroll
        for (int p = 0; p < 4; p++) {
            size_t aoff = (size_t)(m0 + row + p * 32) * K + k0 + col;
            if (AF32) {
                f32x4 v0 = *(const f32x4*)(Af + aoff);
                f32x4 v1 = *(const f32x4*)(Af + aoff + 4);
                av[p] = (us8){ f2bf(v0[0]), f2bf(v0[1]), f2bf(v0[2]), f2bf(v0[3]),
                               f2bf(v1[0]), f2bf(v1[1]), f2bf(v1[2]), f2bf(v1[3]) };
            } else {
                av[p] = *(const us8*)(Ab + aoff);
            }
            size_t boff = (size_t)(n0 + row + p * 32) * K + k0 + col;
            if (BF32) {
                f32x4 v0 = *(const f32x4*)(Bf + boff);
                f32x4 v1 = *(const f32x4*)(Bf + boff + 4);
                bv[p] = (us8){ f2bf(v0[0]), f2bf(v0[1]), f2bf(v0[2]), f2bf(v0[3]),
                               f2bf(v1[0]), f2bf(v1[1]), f2bf(v1[2]), f2bf(v1[3]) };
            } else {
                bv[p] = *(const us8*)(Bb + boff);
            }
        }
        __syncthreads();
#pragma unroll
        for (int p = 0; p < 4; p++) {
            *(us8*)(As + (row + p * 32) * 72 + col) = av[p];
            *(us8*)(Bs + (row + p * 32) * 72 + col) = bv[p];
        }
        __syncthreads();
#pragma unroll
        for (int kk = 0; kk < 2; kk++) {
            us8 af[4], bf[4];
#pragma unroll
            for (int mi = 0; mi < 4; mi++)
                af[mi] = *(const us8*)(As + (wr * 64 + mi * 16 + s) * 72 + kk * 32 + g * 8);
#pragma unroll
            for (int ni = 0; ni < 4; ni++)
                bf[ni] = *(const us8*)(Bs + (wc * 64 + ni * 16 + s) * 72 + kk * 32 + g * 8);
#pragma unroll
            for (int mi = 0; mi < 4; mi++)
#pragma unroll
                for (int ni = 0; ni < 4; ni++)
                    acc[mi][ni] = mfma16(af[mi], bf[ni], acc[mi][ni]);
        }
    }
}

// ---------------- QKV projection ----------------
__global__ __launch_bounds__(256) void gemm_qkv(
    const float* __restrict__ X, const float* __restrict__ Wq,
    const float* __restrict__ Wk, const float* __restrict__ Wv,
    unsigned short* __restrict__ Qb, unsigned short* __restrict__ Kb,
    unsigned short* __restrict__ Vb) {
    __shared__ unsigned short As[128 * 72];
    __shared__ unsigned short Bs[128 * 72];
    const int bm = blockIdx.x & 31, bn = blockIdx.x >> 5;   // 32 x 24
    const int m0 = bm * 128;
    const int which = bn >> 3;                 // 0:Q 1:K 2:V
    const int n0 = (bn & 7) * 128;
    const float* W = which == 0 ? Wq : (which == 1 ? Wk : Wv);
    unsigned short* dst = which == 0 ? Qb : (which == 1 ? Kb : Vb);
    const float scale = which == 0 ? 0.125f : 1.0f;
    f32x4 acc[4][4];
    gemm_core<true, true>(X, W, 1024, m0, n0, As, Bs, acc);
    const int lane = threadIdx.x & 63, wid = threadIdx.x >> 6;
    const int g = lane >> 4, s = lane & 15, wr = wid >> 1, wc = wid & 1;
#pragma unroll
    for (int mi = 0; mi < 4; mi++)
#pragma unroll
        for (int ni = 0; ni < 4; ni++) {
            int n1 = n0 + wc * 64 + ni * 16 + s;
            int hh = n1 >> 6, dd = n1 & 63;
#pragma unroll
            for (int r = 0; r < 4; r++) {
                int mg = m0 + wr * 64 + mi * 16 + 4 * g + r;
                int bb = mg >> 11, tt = mg & 2047;
                dst[((size_t)(bb * 16 + hh) * 2048 + tt) * 64 + dd] = f2bf(acc[mi][ni][r] * scale);
            }
        }
}

// ---------------- V pre-transpose: Vb [bh][t][d] -> VtG [bh][d][t] ----------------
__global__ __launch_bounds__(256) void transpose_v(
    const unsigned short* __restrict__ Vb, unsigned short* __restrict__ VtG) {
    __shared__ unsigned short T[64 * 68];
    const int bh = blockIdx.x >> 5, tt = blockIdx.x & 31;
    const int t0 = tt * 64;
    const unsigned short* src = Vb + (size_t)bh * 2048 * 64;
    unsigned short* dst = VtG + (size_t)bh * 64 * 2048;
    const int r = threadIdx.x >> 3, c = (threadIdx.x & 7) * 8;
#pragma unroll
    for (int p = 0; p < 2; p++) {
        us8 v = *(const us8*)(src + (size_t)(t0 + r + 32 * p) * 64 + c);
        *(us8*)(&T[(r + 32 * p) * 68 + c]) = v;
    }
    __syncthreads();
#pragma unroll
    for (int p = 0; p < 2; p++) {
        int d = r + 32 * p;
        us8 o;
#pragma unroll
        for (int j = 0; j < 8; j++) o[j] = T[(c + j) * 68 + d];
        *(us8*)(dst + (size_t)d * 2048 + t0 + c) = o;
    }
}

// ---------------- flash attention (causal), 512 threads, QBLK=128, KVBLK=64 ----------------
// grid 512: bh = bid>>4 (32), qb = bid&15 (128 q rows each). 8 waves: wave w owns
// q-cols (w&3)*16 of q-subtile (w>>2). Swapped QK^T; V staged from pre-transposed VtG.
// Register-prefetch staging: next tile's K/V loaded right after barrier-2, written next iter.
__global__ __launch_bounds__(512) void attn(
    const unsigned short* __restrict__ Qb, const unsigned short* __restrict__ Kb,
    const unsigned short* __restrict__ VtG, unsigned short* __restrict__ Ob) {
    __shared__ unsigned short Ks[64 * 72];  // [k][d]
    __shared__ unsigned short Vt[64 * 72];  // [d][k]
    const int bh = blockIdx.x >> 4, qb = blockIdx.x & 15;
    const int b = bh >> 4, h = bh & 15;
    const unsigned short* Qp = Qb + (size_t)bh * 2048 * 64;
    const unsigned short* Kp = Kb + (size_t)bh * 2048 * 64;
    const unsigned short* Vp = VtG + (size_t)bh * 64 * 2048;   // [d][t]
    const int tid = threadIdx.x, lane = tid & 63, wid = tid >> 6;
    const int g = lane >> 4, s = lane & 15;
    const int qbase = qb * 128 + (wid >> 2) * 64 + (wid & 3) * 16;
    const int qg = qbase + s;
    us8 qf[2];
    qf[0] = *(const us8*)(Qp + (size_t)qg * 64 + g * 8);
    qf[1] = *(const us8*)(Qp + (size_t)qg * 64 + 32 + g * 8);
    float m_run = -3.0e38f, l_run = 0.f;
    f32x4 o_acc[4];
#pragma unroll
    for (int db = 0; db < 4; db++) o_acc[db] = (f32x4){0.f, 0.f, 0.f, 0.f};
    const int srow = tid >> 3, scol = (tid & 7) * 8;   // srow 0..63 with 512 threads
    const int nt = 2 * qb + 2;
    // prefetch tile 0
    us8 kpre = *(const us8*)(Kp + (size_t)srow * 64 + scol);
    us8 vpre = *(const us8*)(Vp + (size_t)srow * 2048 + scol);
    for (int t = 0; t < nt; ++t) {
        const int kv0 = t * 64;
        __syncthreads();   // previous iteration's LDS reads done
        *(us8*)(Ks + srow * 72 + scol) = kpre;
        *(us8*)(Vt + srow * 72 + scol) = vpre;
        __syncthreads();
        if (t + 1 < nt) {  // prefetch next tile (overlaps compute below)
            kpre = *(const us8*)(Kp + (size_t)(kv0 + 64 + srow) * 64 + scol);
            vpre = *(const us8*)(Vp + (size_t)srow * 2048 + kv0 + 64 + scol);
        }
        if (kv0 > qbase + 15) continue;   // wave-uniform: fully masked tile
        // S^T frags: rows k (4 blocks of 16), cols q (wave's 16)
        float sf[4][4];
#pragma unroll
        for (int f = 0; f < 4; f++) {
            f32x4 a = (f32x4){0.f, 0.f, 0.f, 0.f};
            us8 k0v = *(const us8*)(Ks + (f * 16 + s) * 72 + g * 8);
            us8 k1v = *(const us8*)(Ks + (f * 16 + s) * 72 + 32 + g * 8);
            a = mfma16(k0v, qf[0], a);
            a = mfma16(k1v, qf[1], a);
#pragma unroll
            for (int r = 0; r < 4; r++) sf[f][r] = a[r];
        }
        if (kv0 + 63 > qbase) {   // diagonal-crossing tile: mask k > q
#pragma unroll
            for (int f = 0; f < 4; f++)
#pragma unroll
                for (int r = 0; r < 4; r++)
                    if (kv0 + f * 16 + 4 * g + r > qg) sf[f][r] = -3.0e38f;
        }
        // online softmax per q = s
        float mt = -3.0e38f;
#pragma unroll
        for (int f = 0; f < 4; f++)
#pragma unroll
            for (int r = 0; r < 4; r++) mt = fmaxf(mt, sf[f][r]);
        mt = fmaxf(mt, __shfl_xor(mt, 16));
        mt = fmaxf(mt, __shfl_xor(mt, 32));
        float mnew = fmaxf(m_run, mt);
        float alpha = __builtin_amdgcn_exp2f((m_run - mnew) * LOG2E);
        float psum = 0.f;
#pragma unroll
        for (int f = 0; f < 4; f++)
#pragma unroll
            for (int r = 0; r < 4; r++) {
                float p = __builtin_amdgcn_exp2f((sf[f][r] - mnew) * LOG2E);
                sf[f][r] = p;
                psum += p;
            }
        psum += __shfl_xor(psum, 16);
        psum += __shfl_xor(psum, 32);
        l_run = l_run * alpha + psum;
        m_run = mnew;
        float al[4];
#pragma unroll
        for (int r = 0; r < 4; r++) al[r] = __shfl(alpha, 4 * g + r, 64);
#pragma unroll
        for (int db = 0; db < 4; db++)
#pragma unroll
            for (int r = 0; r < 4; r++) o_acc[db][r] *= al[r];
        // redistribute P (D-layout) -> PV a-frag: lane needs P[q=s][k=kk*32+8g+j]
        us8 pa[2];
#pragma unroll
        for (int kk = 0; kk < 2; kk++) {
#pragma unroll
            for (int j = 0; j < 8; j++) {
                int kl = ((g << 3) + j) & 15;
                int src = ((kl >> 2) << 4) + s;
                float lo = __shfl(sf[kk * 2 + 0][j & 3], src, 64);
                float hi = __shfl(sf[kk * 2 + 1][j & 3], src, 64);
                pa[kk][j] = f2bf((g & 2) ? hi : lo);
            }
        }
        // PV: O[q][d] += P * V ; b-frags from transposed V
#pragma unroll
        for (int db = 0; db < 4; db++) {
            const unsigned short* vrow = Vt + (db * 16 + s) * 72;
            us4 u0 = *(const us4*)(vrow + g * 8);
            us4 u1 = *(const us4*)(vrow + g * 8 + 4);
            us8 vf0 = {u0[0], u0[1], u0[2], u0[3], u1[0], u1[1], u1[2], u1[3]};
            o_acc[db] = mfma16(pa[0], vf0, o_acc[db]);
            us4 u2 = *(const us4*)(vrow + 32 + g * 8);
            us4 u3 = *(const us4*)(vrow + 32 + g * 8 + 4);
            us8 vf1 = {u2[0], u2[1], u2[2], u2[3], u3[0], u3[1], u3[2], u3[3]};
            o_acc[db] = mfma16(pa[1], vf1, o_acc[db]);
        }
    }
    // epilogue: divide by row sum, write O as [B][T][C] bf16
    float li[4];
#pragma unroll
    for (int r = 0; r < 4; r++) li[r] = __shfl(l_run, 4 * g + r, 64);
#pragma unroll
    for (int db = 0; db < 4; db++)
#pragma unroll
        for (int r = 0; r < 4; r++) {
            int qq = qbase + 4 * g + r;
            float v = o_acc[db][r] / li[r];
            Ob[((size_t)(b * 2048) + qq) * 1024 + h * 64 + db * 16 + s] = f2bf(v);
        }
}

// ---------------- output projection ----------------
__global__ __launch_bounds__(256) void gemm_out(
    const unsigned short* __restrict__ O, const float* __restrict__ Wc,
    const float* __restrict__ bc, float* __restrict__ out) {
    __shared__ unsigned short As[128 * 72];
    __shared__ unsigned short Bs[128 * 72];
    const int bm = blockIdx.x & 31, bn = blockIdx.x >> 5;   // 32 x 8
    const int m0 = bm * 128, n0 = bn * 128;
    f32x4 acc[4][4];
    gemm_core<false, true>(O, Wc, 1024, m0, n0, As, Bs, acc);
    const int lane = threadIdx.x & 63, wid = threadIdx.x >> 6;
    const int g = lane >> 4, s = lane & 15, wr = wid >> 1, wc = wid & 1;
#pragma unroll
    for (int mi = 0; mi < 4; mi++)
#pragma unroll
        for (int ni = 0; ni < 4; ni++) {
            int ng = n0 + wc * 64 + ni * 16 + s;
            float bias = bc[ng];
#pragma unroll
            for (int r = 0; r < 4; r++) {
                int mg = m0 + wr * 64 + mi * 16 + 4 * g + r;
                out[(size_t)mg * 1024 + ng] = acc[mi][ni][r] + bias;
            }
        }
}

extern "C" void kernel_launch(void* const* d_in, const int* in_sizes, int n_in,
                              void* d_out, int out_size, void* d_ws, size_t ws_size,
                              hipStream_t stream) {
    const float* x  = (const float*)d_in[0];
    const float* Wq = (const float*)d_in[1];
    const float* Wk = (const float*)d_in[2];
    const float* Wv = (const float*)d_in[3];
    const float* Wc = (const float*)d_in[4];
    const float* bc = (const float*)d_in[5];
    float* out = (float*)d_out;

    if (ws_size < 33554432) {
        fill_sentinel<<<(out_size + 255) / 256, 256, 0, stream>>>(out, out_size);
        return;
    }
    char* w = (char*)d_ws;
    unsigned short* Qb = (unsigned short*)(w);
    unsigned short* Kb = (unsigned short*)(w + 8388608);
    unsigned short* Vb = (unsigned short*)(w + 16777216);
    unsigned short* Ob = (unsigned short*)(w + 25165824);
    // V^T scratch (8 MiB) lives in d_out: dead by the time gemm_out writes out.
    unsigned short* VtG = (unsigned short*)d_out;

    gemm_qkv<<<768, 256, 0, stream>>>(x, Wq, Wk, Wv, Qb, Kb, Vb);
    transpose_v<<<1024, 256, 0, stream>>>(Vb, VtG);
    attn<<<512, 512, 0, stream>>>(Qb, Kb, VtG, Ob);
    gemm_out<<<256, 256, 0, stream>>>(Ob, Wc, bc, out);
}

// Round 5
// 134.590 us; speedup vs baseline: 1.7097x; 1.4350x over previous
//
#include <hip/hip_runtime.h>
#include <hip/hip_bf16.h>

// Fused MHA: B=2, T=2048, C=1024, H=16, dh=64.
// cvt_x -> qkv GEMM (bf16 A, fp32 W) -> V pre-transpose -> balanced flash attention
// (block = q-tiles {i, 31-i}, 33 iters each, 256thr) -> out GEMM (+bias, fp32 out).
// Workspace: Q/K/V/Ob bf16 = 32 MiB. V^T (8MB) + x_bf16 (8MB) live in d_out (dead until gemm_out).

typedef __attribute__((ext_vector_type(4))) float f32x4;
typedef __attribute__((ext_vector_type(4))) unsigned int u32x4;
typedef __attribute__((ext_vector_type(8))) __bf16 bf16x8;
typedef __attribute__((ext_vector_type(8))) unsigned short us8;
typedef __attribute__((ext_vector_type(4))) unsigned short us4;

#define LOG2E 1.4426950408889634f

__device__ __forceinline__ unsigned short f2bf(float f) {
    unsigned u = __builtin_bit_cast(unsigned, f);
    u += 0x7fffu + ((u >> 16) & 1u);   // round-to-nearest-even
    return (unsigned short)(u >> 16);
}

__device__ __forceinline__ unsigned cvt_pk_bf16(float lo, float hi) {
    unsigned r;
    asm("v_cvt_pk_bf16_f32 %0, %1, %2" : "=v"(r) : "v"(lo), "v"(hi));
    return r;
}

__device__ __forceinline__ f32x4 mfma16(us8 a, us8 b, f32x4 c) {
    return __builtin_amdgcn_mfma_f32_16x16x32_bf16(
        __builtin_bit_cast(bf16x8, a), __builtin_bit_cast(bf16x8, b), c, 0, 0, 0);
}

__global__ __launch_bounds__(256) void fill_sentinel(float* __restrict__ out, int n) {
    int i = blockIdx.x * 256 + threadIdx.x;
    if (i < n) out[i] = 12345.0f;
}

__global__ __launch_bounds__(256) void cvt_x(const float* __restrict__ x,
                                             unsigned short* __restrict__ xb) {
    int idx = (blockIdx.x * 256 + threadIdx.x) * 4;
    f32x4 v = *(const f32x4*)(x + idx);
    us4 o = { f2bf(v[0]), f2bf(v[1]), f2bf(v[2]), f2bf(v[3]) };
    *(us4*)(xb + idx) = o;
}

// ---------------- shared GEMM core: C[m][n] = sum_k A[m][k]*Bw[n][k] ----------------
// 128x128 tile, BK=64, 256 threads = 4 waves (2x2), wave does 64x64 (4x4 frags of 16x16).
template <bool AF32, bool BF32>
__device__ __forceinline__ void gemm_core(
    const void* __restrict__ Av, const void* __restrict__ Bv,
    int K, int m0, int n0, unsigned short* As, unsigned short* Bs, f32x4 acc[4][4]) {
    const float* Af = (const float*)Av;
    const unsigned short* Ab = (const unsigned short*)Av;
    const float* Bf = (const float*)Bv;
    const unsigned short* Bb = (const unsigned short*)Bv;
    const int tid = threadIdx.x;
    const int lane = tid & 63, wid = tid >> 6;
    const int g = lane >> 4, s = lane & 15;
    const int wr = wid >> 1, wc = wid & 1;
#pragma unroll
    for (int mi = 0; mi < 4; mi++)
#pragma unroll
        for (int ni = 0; ni < 4; ni++) acc[mi][ni] = (f32x4){0.f, 0.f, 0.f, 0.f};
    const int row = tid >> 3, col = (tid & 7) * 8;
    for (int k0 = 0; k0 < K; k0 += 64) {
        us8 av[4], bv[4];
#pragma unroll
        for (int p = 0; p < 4; p++) {
            size_t aoff = (size_t)(m0 + row + p * 32) * K + k0 + col;
            if (AF32) {
                f32x4 v0 = *(const f32x4*)(Af + aoff);
                f32x4 v1 = *(const f32x4*)(Af + aoff + 4);
                av[p] = (us8){ f2bf(v0[0]), f2bf(v0[1]), f2bf(v0[2]), f2bf(v0[3]),
                               f2bf(v1[0]), f2bf(v1[1]), f2bf(v1[2]), f2bf(v1[3]) };
            } else {
                av[p] = *(const us8*)(Ab + aoff);
            }
            size_t boff = (size_t)(n0 + row + p * 32) * K + k0 + col;
            if (BF32) {
                f32x4 v0 = *(const f32x4*)(Bf + boff);
                f32x4 v1 = *(const f32x4*)(Bf + boff + 4);
                bv[p] = (us8){ f2bf(v0[0]), f2bf(v0[1]), f2bf(v0[2]), f2bf(v0[3]),
                               f2bf(v1[0]), f2bf(v1[1]), f2bf(v1[2]), f2bf(v1[3]) };
            } else {
                bv[p] = *(const us8*)(Bb + boff);
            }
        }
        __syncthreads();
#pragma unroll
        for (int p = 0; p < 4; p++) {
            *(us8*)(As + (row + p * 32) * 72 + col) = av[p];
            *(us8*)(Bs + (row + p * 32) * 72 + col) = bv[p];
        }
        __syncthreads();
#pragma unroll
        for (int kk = 0; kk < 2; kk++) {
            us8 af[4], bf[4];
#pragma unroll
            for (int mi = 0; mi < 4; mi++)
                af[mi] = *(const us8*)(As + (wr * 64 + mi * 16 + s) * 72 + kk * 32 + g * 8);
#pragma unroll
            for (int ni = 0; ni < 4; ni++)
                bf[ni] = *(const us8*)(Bs + (wc * 64 + ni * 16 + s) * 72 + kk * 32 + g * 8);
#pragma unroll
            for (int mi = 0; mi < 4; mi++)
#pragma unroll
                for (int ni = 0; ni < 4; ni++)
                    acc[mi][ni] = mfma16(af[mi], bf[ni], acc[mi][ni]);
        }
    }
}

// ---------------- QKV projection: X(bf16) x W*(f32)^T ----------------
__global__ __launch_bounds__(256) void gemm_qkv(
    const unsigned short* __restrict__ X, const float* __restrict__ Wq,
    const float* __restrict__ Wk, const float* __restrict__ Wv,
    unsigned short* __restrict__ Qb, unsigned short* __restrict__ Kb,
    unsigned short* __restrict__ Vb) {
    __shared__ unsigned short As[128 * 72];
    __shared__ unsigned short Bs[128 * 72];
    const int bm = blockIdx.x & 31, bn = blockIdx.x >> 5;   // 32 x 24
    const int m0 = bm * 128;
    const int which = bn >> 3;                 // 0:Q 1:K 2:V
    const int n0 = (bn & 7) * 128;
    const float* W = which == 0 ? Wq : (which == 1 ? Wk : Wv);
    unsigned short* dst = which == 0 ? Qb : (which == 1 ? Kb : Vb);
    const float scale = which == 0 ? 0.125f : 1.0f;
    f32x4 acc[4][4];
    gemm_core<false, true>(X, W, 1024, m0, n0, As, Bs, acc);
    const int lane = threadIdx.x & 63, wid = threadIdx.x >> 6;
    const int g = lane >> 4, s = lane & 15, wr = wid >> 1, wc = wid & 1;
#pragma unroll
    for (int mi = 0; mi < 4; mi++)
#pragma unroll
        for (int ni = 0; ni < 4; ni++) {
            int n1 = n0 + wc * 64 + ni * 16 + s;
            int hh = n1 >> 6, dd = n1 & 63;
#pragma unroll
            for (int r = 0; r < 4; r++) {
                int mg = m0 + wr * 64 + mi * 16 + 4 * g + r;
                int bb = mg >> 11, tt = mg & 2047;
                dst[((size_t)(bb * 16 + hh) * 2048 + tt) * 64 + dd] = f2bf(acc[mi][ni][r] * scale);
            }
        }
}

// ---------------- V pre-transpose: Vb [bh][t][d] -> VtG [bh][d][t] ----------------
__global__ __launch_bounds__(256) void transpose_v(
    const unsigned short* __restrict__ Vb, unsigned short* __restrict__ VtG) {
    __shared__ unsigned short T[64 * 68];
    const int bh = blockIdx.x >> 5, tt = blockIdx.x & 31;
    const int t0 = tt * 64;
    const unsigned short* src = Vb + (size_t)bh * 2048 * 64;
    unsigned short* dst = VtG + (size_t)bh * 64 * 2048;
    const int r = threadIdx.x >> 3, c = (threadIdx.x & 7) * 8;
#pragma unroll
    for (int p = 0; p < 2; p++) {
        us8 v = *(const us8*)(src + (size_t)(t0 + r + 32 * p) * 64 + c);
        *(us8*)(&T[(r + 32 * p) * 68 + c]) = v;
    }
    __syncthreads();
#pragma unroll
    for (int p = 0; p < 2; p++) {
        int d = r + 32 * p;
        us8 o;
#pragma unroll
        for (int j = 0; j < 8; j++) o[j] = T[(c + j) * 68 + d];
        *(us8*)(dst + (size_t)d * 2048 + t0 + c) = o;
    }
}

// ---------------- flash attention (causal), balanced pair blocks ----------------
// grid 512: bh = bid>>4 (32), i = bid&15. Block processes q-tile A=i (iters 0..i),
// then q-tile B=31-i (iters i+1..32): exactly 33 KV-tile iterations per block.
// 256 thr = 4 waves; wave w owns q-cols w*16..+15 of the current tile.
// Swapped QK^T; V from pre-transposed VtG; register prefetch of next KV tile.
#define ATTN_EPILOGUE(QB0, OA, LR)                                              \
    {                                                                           \
        float li[4];                                                            \
        _Pragma("unroll") for (int r = 0; r < 4; r++)                           \
            li[r] = __shfl((LR), 4 * g + r, 64);                                \
        _Pragma("unroll") for (int db = 0; db < 4; db++)                        \
            _Pragma("unroll") for (int r = 0; r < 4; r++) {                     \
                int qq = (QB0) + 4 * g + r;                                     \
                float v = (OA)[db][r] / li[r];                                  \
                Ob[((size_t)(b * 2048) + qq) * 1024 + h * 64 + db * 16 + s] = f2bf(v); \
            }                                                                   \
    }

__global__ __launch_bounds__(256) void attn(
    const unsigned short* __restrict__ Qb, const unsigned short* __restrict__ Kb,
    const unsigned short* __restrict__ VtG, unsigned short* __restrict__ Ob) {
    __shared__ unsigned short Ks[64 * 72];  // [k][d]
    __shared__ unsigned short Vt[64 * 72];  // [d][k]
    const int bh = blockIdx.x >> 4, i = blockIdx.x & 15;
    const int b = bh >> 4, h = bh & 15;
    const unsigned short* Qp = Qb + (size_t)bh * 2048 * 64;
    const unsigned short* Kp = Kb + (size_t)bh * 2048 * 64;
    const unsigned short* Vp = VtG + (size_t)bh * 64 * 2048;   // [d][t]
    const int tid = threadIdx.x, lane = tid & 63, wid = tid >> 6;
    const int g = lane >> 4, s = lane & 15;
    const int qbA = i * 64 + wid * 16;          // tile A: rows [i*64, +64)
    const int qbB = (31 - i) * 64 + wid * 16;   // tile B: rows [(31-i)*64, +64)
    const int qgA = qbA + s, qgB = qbB + s;
    us8 qfA[2], qfB[2];
    qfA[0] = *(const us8*)(Qp + (size_t)qgA * 64 + g * 8);
    qfA[1] = *(const us8*)(Qp + (size_t)qgA * 64 + 32 + g * 8);
    qfB[0] = *(const us8*)(Qp + (size_t)qgB * 64 + g * 8);
    qfB[1] = *(const us8*)(Qp + (size_t)qgB * 64 + 32 + g * 8);
    float m_run = -3.0e38f, l_run = 0.f;
    f32x4 o_acc[4];
#pragma unroll
    for (int db = 0; db < 4; db++) o_acc[db] = (f32x4){0.f, 0.f, 0.f, 0.f};
    const int srow = tid >> 3, scol = (tid & 7) * 8;   // srow 0..31
    us8 kpre[2], vpre[2];
#pragma unroll
    for (int p = 0; p < 2; p++) {
        kpre[p] = *(const us8*)(Kp + (size_t)(srow + 32 * p) * 64 + scol);
        vpre[p] = *(const us8*)(Vp + (size_t)(srow + 32 * p) * 2048 + scol);
    }
    for (int it = 0; it <= 32; ++it) {
        const bool qsel = it > i;
        const int kv0 = (qsel ? it - i - 1 : it) * 64;
        __syncthreads();   // previous iteration's LDS reads done
#pragma unroll
        for (int p = 0; p < 2; p++) {
            *(us8*)(Ks + (srow + 32 * p) * 72 + scol) = kpre[p];
            *(us8*)(Vt + (srow + 32 * p) * 72 + scol) = vpre[p];
        }
        __syncthreads();
        if (it < 32) {   // prefetch next tile (overlaps compute below)
            const int nx = it + 1;
            const int nkv0 = (nx > i ? nx - i - 1 : nx) * 64;
#pragma unroll
            for (int p = 0; p < 2; p++) {
                kpre[p] = *(const us8*)(Kp + (size_t)(nkv0 + srow + 32 * p) * 64 + scol);
                vpre[p] = *(const us8*)(Vp + (size_t)(srow + 32 * p) * 2048 + nkv0 + scol);
            }
        }
        if (it == i + 1) {   // tile A finished last iteration: emit + reset
            ATTN_EPILOGUE(qbA, o_acc, l_run);
            m_run = -3.0e38f; l_run = 0.f;
#pragma unroll
            for (int db = 0; db < 4; db++) o_acc[db] = (f32x4){0.f, 0.f, 0.f, 0.f};
        }
        const int qg = qsel ? qgB : qgA;
        const us8* qf = qsel ? qfB : qfA;
        // S^T frags: rows k (4 blocks of 16), cols q (wave's 16)
        float sf[4][4];
        __builtin_amdgcn_s_setprio(1);
#pragma unroll
        for (int f = 0; f < 4; f++) {
            f32x4 a = (f32x4){0.f, 0.f, 0.f, 0.f};
            us8 k0v = *(const us8*)(Ks + (f * 16 + s) * 72 + g * 8);
            us8 k1v = *(const us8*)(Ks + (f * 16 + s) * 72 + 32 + g * 8);
            a = mfma16(k0v, qf[0], a);
            a = mfma16(k1v, qf[1], a);
#pragma unroll
            for (int r = 0; r < 4; r++) sf[f][r] = a[r];
        }
        __builtin_amdgcn_s_setprio(0);
        const bool diag = qsel ? (it == 32) : (it == i);
        if (diag) {   // diagonal tile: mask k > q
#pragma unroll
            for (int f = 0; f < 4; f++)
#pragma unroll
                for (int r = 0; r < 4; r++)
                    if (kv0 + f * 16 + 4 * g + r > qg) sf[f][r] = -3.0e38f;
        }
        // online softmax per q = s
        float mt = -3.0e38f;
#pragma unroll
        for (int f = 0; f < 4; f++)
#pragma unroll
            for (int r = 0; r < 4; r++) mt = fmaxf(mt, sf[f][r]);
        mt = fmaxf(mt, __shfl_xor(mt, 16));
        mt = fmaxf(mt, __shfl_xor(mt, 32));
        float mnew = fmaxf(m_run, mt);
        float alpha = __builtin_amdgcn_exp2f((m_run - mnew) * LOG2E);
        float psum = 0.f;
#pragma unroll
        for (int f = 0; f < 4; f++)
#pragma unroll
            for (int r = 0; r < 4; r++) {
                float p = __builtin_amdgcn_exp2f((sf[f][r] - mnew) * LOG2E);
                sf[f][r] = p;
                psum += p;
            }
        psum += __shfl_xor(psum, 16);
        psum += __shfl_xor(psum, 32);
        l_run = l_run * alpha + psum;
        m_run = mnew;
        float al[4];
#pragma unroll
        for (int r = 0; r < 4; r++) al[r] = __shfl(alpha, 4 * g + r, 64);
#pragma unroll
        for (int db = 0; db < 4; db++)
#pragma unroll
            for (int r = 0; r < 4; r++) o_acc[db][r] *= al[r];
        // packed redistribute: P (D-layout) -> PV a-frag. Lane packs sf pairs to bf16,
        // then 16 dword shuffles. pa[kk] dwords m: j=2m,2m+1; f = kk*2+(g>>1);
        // src lane = (2*(g&1) + (m>>1))*16 + s; value = pk[f][m&1].
        unsigned pk[4][2];
#pragma unroll
        for (int f = 0; f < 4; f++)
#pragma unroll
            for (int hh2 = 0; hh2 < 2; hh2++)
                pk[f][hh2] = cvt_pk_bf16(sf[f][2 * hh2], sf[f][2 * hh2 + 1]);
        const int srcA = 32 * (g & 1) + s, srcB = srcA + 16;
        const bool ghi = g >= 2;
        us8 pa[2];
#pragma unroll
        for (int kk = 0; kk < 2; kk++) {
            unsigned e0 = __shfl(pk[kk * 2][0], srcA, 64);
            unsigned e1 = __shfl(pk[kk * 2][1], srcA, 64);
            unsigned e2 = __shfl(pk[kk * 2][0], srcB, 64);
            unsigned e3 = __shfl(pk[kk * 2][1], srcB, 64);
            unsigned o0 = __shfl(pk[kk * 2 + 1][0], srcA, 64);
            unsigned o1 = __shfl(pk[kk * 2 + 1][1], srcA, 64);
            unsigned o2 = __shfl(pk[kk * 2 + 1][0], srcB, 64);
            unsigned o3 = __shfl(pk[kk * 2 + 1][1], srcB, 64);
            u32x4 dw = { ghi ? o0 : e0, ghi ? o1 : e1, ghi ? o2 : e2, ghi ? o3 : e3 };
            pa[kk] = __builtin_bit_cast(us8, dw);
        }
        // PV: O[q][d] += P * V ; b-frags straight us8 from transposed V (16B-aligned)
        __builtin_amdgcn_s_setprio(1);
#pragma unroll
        for (int db = 0; db < 4; db++) {
            const unsigned short* vrow = Vt + (db * 16 + s) * 72;
            us8 vf0 = *(const us8*)(vrow + g * 8);
            o_acc[db] = mfma16(pa[0], vf0, o_acc[db]);
            us8 vf1 = *(const us8*)(vrow + 32 + g * 8);
            o_acc[db] = mfma16(pa[1], vf1, o_acc[db]);
        }
        __builtin_amdgcn_s_setprio(0);
    }
    ATTN_EPILOGUE(qbB, o_acc, l_run);
}

// ---------------- output projection ----------------
__global__ __launch_bounds__(256) void gemm_out(
    const unsigned short* __restrict__ O, const float* __restrict__ Wc,
    const float* __restrict__ bc, float* __restrict__ out) {
    __shared__ unsigned short As[128 * 72];
    __shared__ unsigned short Bs[128 * 72];
    const int bm = blockIdx.x & 31, bn = blockIdx.x >> 5;   // 32 x 8
    const int m0 = bm * 128, n0 = bn * 128;
    f32x4 acc[4][4];
    gemm_core<false, true>(O, Wc, 1024, m0, n0, As, Bs, acc);
    const int lane = threadIdx.x & 63, wid = threadIdx.x >> 6;
    const int g = lane >> 4, s = lane & 15, wr = wid >> 1, wc = wid & 1;
#pragma unroll
    for (int mi = 0; mi < 4; mi++)
#pragma unroll
        for (int ni = 0; ni < 4; ni++) {
            int ng = n0 + wc * 64 + ni * 16 + s;
            float bias = bc[ng];
#pragma unroll
            for (int r = 0; r < 4; r++) {
                int mg = m0 + wr * 64 + mi * 16 + 4 * g + r;
                out[(size_t)mg * 1024 + ng] = acc[mi][ni][r] + bias;
            }
        }
}

extern "C" void kernel_launch(void* const* d_in, const int* in_sizes, int n_in,
                              void* d_out, int out_size, void* d_ws, size_t ws_size,
                              hipStream_t stream) {
    const float* x  = (const float*)d_in[0];
    const float* Wq = (const float*)d_in[1];
    const float* Wk = (const float*)d_in[2];
    const float* Wv = (const float*)d_in[3];
    const float* Wc = (const float*)d_in[4];
    const float* bc = (const float*)d_in[5];
    float* out = (float*)d_out;

    if (ws_size < 33554432) {
        fill_sentinel<<<(out_size + 255) / 256, 256, 0, stream>>>(out, out_size);
        return;
    }
    char* w = (char*)d_ws;
    unsigned short* Qb = (unsigned short*)(w);
    unsigned short* Kb = (unsigned short*)(w + 8388608);
    unsigned short* Vb = (unsigned short*)(w + 16777216);
    unsigned short* Ob = (unsigned short*)(w + 25165824);
    // d_out (16 MB fp32) doubles as scratch until gemm_out: V^T [0,8MB), x_bf16 [8MB,16MB).
    unsigned short* VtG = (unsigned short*)d_out;
    unsigned short* xb  = (unsigned short*)((char*)d_out + 8388608);

    cvt_x<<<4096, 256, 0, stream>>>(x, xb);
    gemm_qkv<<<768, 256, 0, stream>>>(xb, Wq, Wk, Wv, Qb, Kb, Vb);
    transpose_v<<<1024, 256, 0, stream>>>(Vb, VtG);
    attn<<<512, 256, 0, stream>>>(Qb, Kb, VtG, Ob);
    gemm_out<<<256, 256, 0, stream>>>(Ob, Wc, bc, out);
}